// Round 1
// baseline (440.037 us; speedup 1.0000x reference)
//
#include <hip/hip_runtime.h>

#define IMG_W   512
#define IMG_HW  (512*512)
#define PATCH   16
#define NPATCH  1024      // (512/16)^2
#define NCELL   32
#define NG      20
#define FEAT    64
#define EPSF    1e-6f

typedef unsigned long long ull;

__device__ __forceinline__ float wave_sum(float v) {
    #pragma unroll
    for (int o = 1; o < 64; o <<= 1) v += __shfl_xor(v, o, 64);
    return v;
}

__device__ __forceinline__ float block_sum(float v, float* sP, int t) {
    #pragma unroll
    for (int o = 1; o < 64; o <<= 1) v += __shfl_xor(v, o, 64);
    __syncthreads();                       // protect sP from previous use
    if ((t & 63) == 0) sP[t >> 6] = v;
    __syncthreads();
    return sP[0] + sP[1] + sP[2] + sP[3];
}

// ---------------------------------------------------------------------------
// Kernel 1: ONE WAVE PER PATCH, zero barriers. 2048 blocks x 256 (4 waves).
// UNCHANGED from the 448.3 µs version — entropy math is bit-identical to the
// numpy f32 reference so the downstream argmax selects the same patch.
// ---------------------------------------------------------------------------
__global__ __launch_bounds__(256) void k_entropy(const float* __restrict__ HE,
                                                 float* __restrict__ ent) {
    __shared__ int hist[4][256];           // 4 KB: one private histogram per wave
    int t = threadIdx.x;
    int w = t >> 6, l = t & 63;
    int pid = blockIdx.x * 4 + w;          // global patch id
    int b  = pid >> 10;
    int p  = pid & 1023;
    int pr = p >> 5, pc = p & 31;
    int r  = l >> 2, q = l & 3;            // row in patch, float4-quad in row
    size_t base = (size_t)b * 3 * IMG_HW
                + (size_t)(pr * PATCH + r) * IMG_W + pc * PATCH + q * 4;
    float4 cr = *(const float4*)(HE + base);
    float4 cg = *(const float4*)(HE + base + IMG_HW);
    float4 cb = *(const float4*)(HE + base + 2 * IMG_HW);
    // forbid fma contraction: must match numpy f32 (mul,mul,add,mul,add)
    float gray[4];
    gray[0] = __fadd_rn(__fadd_rn(__fmul_rn(0.2989f, cr.x), __fmul_rn(0.587f, cg.x)),
                        __fmul_rn(0.114f, cb.x));
    gray[1] = __fadd_rn(__fadd_rn(__fmul_rn(0.2989f, cr.y), __fmul_rn(0.587f, cg.y)),
                        __fmul_rn(0.114f, cb.y));
    gray[2] = __fadd_rn(__fadd_rn(__fmul_rn(0.2989f, cr.z), __fmul_rn(0.587f, cg.z)),
                        __fmul_rn(0.114f, cb.z));
    gray[3] = __fadd_rn(__fadd_rn(__fmul_rn(0.2989f, cr.w), __fmul_rn(0.587f, cg.w)),
                        __fmul_rn(0.114f, cb.w));
    // exact wave min/max (order-independent)
    float mn = fminf(fminf(gray[0], gray[1]), fminf(gray[2], gray[3]));
    float mx = fmaxf(fmaxf(gray[0], gray[1]), fmaxf(gray[2], gray[3]));
    #pragma unroll
    for (int o = 1; o < 64; o <<= 1) {
        mn = fminf(mn, __shfl_xor(mn, o, 64));
        mx = fmaxf(mx, __shfl_xor(mx, o, 64));
    }
    float denom = __fadd_rn(__fadd_rn(mx, -mn), 1e-8f);
    // zero my wave's histogram (each lane zeros the 4 bins it later reads)
    int* h = hist[w];
    h[l] = 0; h[l + 64] = 0; h[l + 128] = 0; h[l + 192] = 0;
    // binning byte-identical to Round 1/3
    #pragma unroll
    for (int j = 0; j < 4; ++j) {
        float v = __fdiv_rn(__fadd_rn(gray[j], -mn), denom);
        int bin = (int)__fmul_rn(v, 256.0f);
        bin = min(max(bin, 0), 255);
        atomicAdd(&h[bin], 1);             // same-wave LDS: ordered, exact
    }
    // entropy terms, tree-compatible combine
    float f[4];
    #pragma unroll
    for (int j = 0; j < 4; ++j) {
        int c = h[l + j * 64];
        float term = 0.0f;
        if (c > 0) {
            float prob = (float)c / 256.0f;   // 256.0f + 1e-8f == 256.0f
            term = prob * log2f(prob);
        }
        f[j] = term;
    }
    float s = __fadd_rn(__fadd_rn(f[0], f[2]), __fadd_rn(f[1], f[3]));
    #pragma unroll
    for (int o = 32; o >= 1; o >>= 1) s = __fadd_rn(s, __shfl_xor(s, o, 64));
    if (l == 0) ent[pid] = 0.0f - s;          // avoid -0.0f
}

// ---------------------------------------------------------------------------
// Kernel 1b (NEW): argmax hoisted out of k_moments. One block per image.
// Key packing identical to the verified version: (ent_bits<<32) | ~p gives
// first-index tie-break, so the selected patch is bit-identical.
// ---------------------------------------------------------------------------
__global__ __launch_bounds__(256) void k_argmax(const float* __restrict__ ent,
                                                int* __restrict__ bestp) {
    __shared__ ull sK[4];
    int t = threadIdx.x, b = blockIdx.x;
    ull best = 0ull;
    for (int i = t; i < NPATCH; i += 256) {
        float e = ent[b * NPATCH + i];
        ull k = ((ull)__float_as_uint(e) << 32)
              | (ull)(0xFFFFFFFFu - (unsigned)i);
        best = best > k ? best : k;
    }
    #pragma unroll
    for (int o = 1; o < 64; o <<= 1) {
        ull other = __shfl_xor(best, o, 64);
        best = best > other ? best : other;
    }
    if ((t & 63) == 0) sK[t >> 6] = best;
    __syncthreads();
    if (t == 0) {
        ull key = sK[0];
        #pragma unroll
        for (int wv = 1; wv < 4; ++wv) key = key > sK[wv] ? key : sK[wv];
        bestp[b] = (int)(0xFFFFFFFFu - (unsigned)(key & 0xFFFFFFFFull));
    }
}

// ---------------------------------------------------------------------------
// Kernel 2 (RESTRUCTURED): one block per (image, cell).
//  - patch id read from bestp (no redundant per-block argmax scan)
//  - mask moments: exact integer-valued wave sums, identical to before
//  - channel phase: 23 channels distributed over 4 waves (6/6/6/5).
//    Each wave loads a channel patch as float4 (64 lanes x 16B = the full
//    16x16 patch), multiplies against the LDS-cached mask, and the 6 loads
//    per wave are issued back-to-back before any reduction so L2/HBM
//    latency overlaps across channels instead of serializing 23-deep.
// feat rows per image: 0=cx, 1=cy, 2..24 = E for channel 0..22.
// ---------------------------------------------------------------------------
__global__ __launch_bounds__(256) void k_moments(
    const float* __restrict__ HE, const float* __restrict__ HQ,
    const int*   __restrict__ M,  const int* __restrict__ bestp,
    float* __restrict__ feat)
{
    __shared__ __align__(16) float sM[256];   // mask patch as float
    __shared__ float sE[23];
    __shared__ float sP[3][4];
    int t = threadIdx.x;
    int b = blockIdx.x >> 5, n = blockIdx.x & 31;

    unsigned p = (unsigned)bestp[b];
    int y0 = (int)(p >> 5) * PATCH;
    int x0 = (int)(p & 31) * PATCH;
    int py = t >> 4, px = t & 15;
    size_t off = (size_t)(y0 + py) * IMG_W + (x0 + px);

    float mv = (float)M[((size_t)b * NCELL + n) * IMG_HW + off];
    sM[t] = mv;
    int w = t >> 6, lane = t & 63;
    // mask moments (integer-valued sums -> exact in fp32, any order)
    float s0 = wave_sum(mv);
    float s1 = wave_sum(mv * (float)px);
    float s2 = wave_sum(mv * (float)py);
    if (lane == 0) { sP[0][w] = s0; sP[1][w] = s1; sP[2][w] = s2; }
    __syncthreads();                        // sM visible to all waves

    // channel phase: wave w handles channels {w, w+4, w+8, ...}
    // lane covers 4 px: row r = lane>>2, quad q = lane&3  (float4-aligned)
    int r = lane >> 2, q = lane & 3;
    size_t poff = (size_t)(y0 + r) * IMG_W + x0 + q * 4;
    float4 m4 = *(const float4*)&sM[r * 16 + q * 4];
    float part[6];
    #pragma unroll
    for (int kk = 0; kk < 6; ++kk) {        // issue all loads first (MLP)
        int c = w + kk * 4;
        part[kk] = 0.0f;
        if (c < 23) {
            const float* cp = (c < 3) ? HE + ((size_t)b * 3 + c) * IMG_HW
                                      : HQ + ((size_t)b * NG + (c - 3)) * IMG_HW;
            float4 v = *(const float4*)(cp + poff);
            part[kk] = v.x * m4.x + v.y * m4.y + v.z * m4.z + v.w * m4.w;
        }
    }
    #pragma unroll
    for (int kk = 0; kk < 6; ++kk) {        // 6 independent shuffle trees
        int c = w + kk * 4;
        if (c < 23) {                       // wave-uniform branch (c dep on w,kk)
            float s = wave_sum(part[kk]);
            if (lane == 0) sE[c] = s;
        }
    }
    __syncthreads();
    if (t < 25) {
        float ms = sP[0][0] + sP[0][1] + sP[0][2] + sP[0][3];
        float s;
        if (t == 0)      s = (sP[1][0] + sP[1][1] + sP[1][2] + sP[1][3]) / ms;   // cx
        else if (t == 1) s = (sP[2][0] + sP[2][1] + sP[2][2] + sP[2][3]) / ms;   // cy
        else             s = sE[t - 2] / (ms + EPSF);                            // E
        feat[((size_t)b * 25 + t) * NCELL + n] = s;
    }
}

// ---------------------------------------------------------------------------
// Kernel 3: one block per image. Adjacency + GNN + corr + ssim, all in LDS
// with padded strides (129 / 65 / 33) -> conflict-free. UNCHANGED.
// ---------------------------------------------------------------------------
__global__ __launch_bounds__(256) void k_gnn(
    const float* __restrict__ w1, const float* __restrict__ b1,
    const float* __restrict__ w2, const float* __restrict__ b2,
    const float* __restrict__ feat, float* __restrict__ losses)
{
    __shared__ float sF[2][NCELL * 129];   // 33024 B, concat features [32][128]+pad
    __shared__ float sU[4160];             // sT[32][65] | sH[32][65]; later sC[2][1024]
    __shared__ float sAdj[NCELL * 33];     // padded adjacency
    __shared__ float sCx[32], sCy[32], sRow[32];
    __shared__ float sMu[128], sSd[128];
    __shared__ float sP[4];

    int t = threadIdx.x, b = blockIdx.x;
    const float* fb = feat + (size_t)b * 25 * NCELL;

    if (t < 32) { sCx[t] = fb[t]; sCy[t] = fb[NCELL + t]; }
    for (int i = t; i < 2 * NCELL * 129; i += 256) ((float*)sF)[i] = 0.0f;
    __syncthreads();

    // fill E into low halves (zero padding already in place)
    for (int i = t; i < 23 * NCELL; i += 256) {
        int ch = i >> 5, n = i & 31;
        float v = fb[(2 + ch) * NCELL + n];
        if (ch < 3) sF[0][n * 129 + ch]       = v;
        else        sF[1][n * 129 + (ch - 3)] = v;
    }
    // adjacency
    for (int i = t; i < NCELL * NCELL; i += 256) {
        int ii = i >> 5, jj = i & 31;
        float dx = sCx[ii] - sCx[jj], dy = sCy[ii] - sCy[jj];
        float dist = sqrtf(fmaxf(dx * dx + dy * dy, 0.0f));
        sAdj[ii * 33 + jj] = expf(-dist / (3.0f + EPSF));
    }
    __syncthreads();
    if (t < 32) {
        float s = 0.0f;
        #pragma unroll
        for (int j = 0; j < 32; ++j) s += sAdj[t * 33 + j];
        sRow[t] = s + 1e-8f;
    }
    __syncthreads();
    for (int i = t; i < NCELL * NCELL; i += 256)
        sAdj[(i >> 5) * 33 + (i & 31)] /= sRow[i >> 5];
    __syncthreads();

    // ---- GNN (2 matrices) ----
    float* sT = sU;            // [32][65]
    float* sH = sU + 2080;     // [32][65]
    for (int m = 0; m < 2; ++m) {
        float* F = sF[m];
        // t1 = adj @ X (X = F[:, :64])
        for (int idx = t; idx < NCELL * FEAT; idx += 256) {
            int n = idx >> 6, f = idx & 63;
            float s = 0.0f;
            #pragma unroll
            for (int k = 0; k < 32; ++k) s += sAdj[n * 33 + k] * F[k * 129 + f];
            sT[n * 65 + f] = s;
        }
        __syncthreads();
        // h = relu(t1 @ w1.T + b1)
        for (int idx = t; idx < NCELL * FEAT; idx += 256) {
            int n = idx >> 6, f = idx & 63;
            const float4* wr = (const float4*)(w1 + (size_t)f * FEAT);
            const float*  tp = &sT[n * 65];
            float s = b1[f];
            #pragma unroll
            for (int k4 = 0; k4 < 16; ++k4) {
                float4 w4 = wr[k4];
                s += tp[k4*4+0]*w4.x + tp[k4*4+1]*w4.y + tp[k4*4+2]*w4.z + tp[k4*4+3]*w4.w;
            }
            sH[n * 65 + f] = fmaxf(s, 0.0f);
        }
        __syncthreads();
        // t2 = adj @ h  -> sT (t1 dead)
        for (int idx = t; idx < NCELL * FEAT; idx += 256) {
            int n = idx >> 6, f = idx & 63;
            float s = 0.0f;
            #pragma unroll
            for (int k = 0; k < 32; ++k) s += sAdj[n * 33 + k] * sH[k * 65 + f];
            sT[n * 65 + f] = s;
        }
        __syncthreads();
        // out = relu(t2 @ w2.T + b2) -> F[:, 64:128]
        for (int idx = t; idx < NCELL * FEAT; idx += 256) {
            int n = idx >> 6, f = idx & 63;
            const float4* wr = (const float4*)(w2 + (size_t)f * FEAT);
            const float*  tp = &sT[n * 65];
            float s = b2[f];
            #pragma unroll
            for (int k4 = 0; k4 < 16; ++k4) {
                float4 w4 = wr[k4];
                s += tp[k4*4+0]*w4.x + tp[k4*4+1]*w4.y + tp[k4*4+2]*w4.z + tp[k4*4+3]*w4.w;
            }
            F[n * 129 + 64 + f] = fmaxf(s, 0.0f);
        }
        __syncthreads();
    }

    // ---- standardize + corr (sT/sH dead; sC overlays sU) ----
    float* sC = sU;            // [2][1024]
    for (int m = 0; m < 2; ++m) {
        float* F = sF[m];
        if (t < 128) {
            float s = 0.0f;
            #pragma unroll
            for (int n2 = 0; n2 < 32; ++n2) s += F[n2 * 129 + t];
            float mu = s / 32.0f;
            float ss = 0.0f;
            #pragma unroll
            for (int n2 = 0; n2 < 32; ++n2) { float d = F[n2 * 129 + t] - mu; ss += d * d; }
            sMu[t] = mu;
            sSd[t] = sqrtf(ss / 31.0f);    // ddof=1
        }
        __syncthreads();
        for (int i = t; i < NCELL * 128; i += 256) {
            int n2 = i >> 7, c = i & 127;
            F[n2 * 129 + c] = (F[n2 * 129 + c] - sMu[c]) / (sSd[c] + EPSF);
        }
        __syncthreads();
        for (int i = t; i < NCELL * NCELL; i += 256) {
            int ii = i >> 5, jj = i & 31;
            float s = 0.0f;
            #pragma unroll
            for (int k = 0; k < 128; ++k) s += F[ii * 129 + k] * F[jj * 129 + k];
            s /= 127.0f;
            sC[m * 1024 + i] = fminf(fmaxf(s, -1.0f), 1.0f);
        }
        __syncthreads();
    }

    // ---- ssim ----
    float px = 0.0f, py = 0.0f;
    for (int e = t; e < 1024; e += 256) { px += sC[e]; py += sC[1024 + e]; }
    float mux = block_sum(px, sP, t) / 1024.0f;
    float muy = block_sum(py, sP, t) / 1024.0f;
    float va = 0.0f, vb = 0.0f, vc = 0.0f;
    for (int e = t; e < 1024; e += 256) {
        float dx = sC[e] - mux, dy = sC[1024 + e] - muy;
        va += dx * dx; vb += dy * dy; vc += dx * dy;
    }
    float sxv = block_sum(va, sP, t) / 1023.0f;   // var ddof=1
    float syv = block_sum(vb, sP, t) / 1023.0f;
    float sxy = block_sum(vc, sP, t) / 1024.0f;   // covariance is a mean
    if (t == 0) {
        const float C1 = 1e-4f, C2 = 1e-4f;
        float ssim = (2.0f * mux * muy + C1) * (2.0f * sxy + C2)
                   / ((mux * mux + muy * muy + C1) * (sxv + syv + C2));
        ssim = fminf(fmaxf(ssim, 0.0f), 1.0f);
        losses[b] = 1.0f - ssim;
    }
}

// ---------------------------------------------------------------------------
// Kernel 4: deterministic final sum / B
// ---------------------------------------------------------------------------
__global__ void k_final(const float* __restrict__ losses, float* __restrict__ out, int B) {
    if (threadIdx.x == 0) {
        float s = 0.0f;
        for (int i = 0; i < B; ++i) s += losses[i];
        out[0] = s / (float)B;
    }
}

extern "C" void kernel_launch(void* const* d_in, const int* in_sizes, int n_in,
                              void* d_out, int out_size, void* d_ws, size_t ws_size,
                              hipStream_t stream) {
    const float* HE = (const float*)d_in[0];
    const float* HQ = (const float*)d_in[1];
    const int*   M  = (const int*)d_in[2];
    const float* w1 = (const float*)d_in[3];
    const float* b1 = (const float*)d_in[4];
    const float* w2 = (const float*)d_in[5];
    const float* b2 = (const float*)d_in[6];
    float* out = (float*)d_out;

    int B = in_sizes[0] / (3 * IMG_HW);   // 8

    // ws layout: ent[B*1024] f32 | losses[B] f32 | feat[B][25][32] f32 | bestp[B] i32
    float* ent    = (float*)d_ws;
    float* losses = (float*)((char*)d_ws + (size_t)B * NPATCH * 4);
    float* feat   = (float*)((char*)losses + (size_t)B * 4);
    int*   bestp  = (int*)((char*)feat + (size_t)B * 25 * NCELL * 4);

    hipLaunchKernelGGL(k_entropy, dim3(B * NPATCH / 4), dim3(256), 0, stream, HE, ent);
    hipLaunchKernelGGL(k_argmax,  dim3(B),              dim3(256), 0, stream, ent, bestp);
    hipLaunchKernelGGL(k_moments, dim3(B * NCELL),      dim3(256), 0, stream, HE, HQ, M, bestp, feat);
    hipLaunchKernelGGL(k_gnn,     dim3(B),              dim3(256), 0, stream, w1, b1, w2, b2, feat, losses);
    hipLaunchKernelGGL(k_final,   dim3(1),              dim3(1),   0, stream, losses, out, B);
}